// Round 2
// baseline (1749.033 us; speedup 1.0000x reference)
//
#include <hip/hip_runtime.h>
#include <hip/hip_bf16.h>

// Problem constants
constexpr int B_ = 4, L_ = 2048, D_ = 512, H_ = 8, C_ = 3, DH_ = 64;
constexpr long long OUT0 = (long long)B_ * L_ * D_;   // 4194304 elements (out), probs follows

typedef short bf16x8 __attribute__((ext_vector_type(8)));
typedef float floatx4 __attribute__((ext_vector_type(4)));

__device__ __forceinline__ float bf2f(short s) {
    union { unsigned u; float f; } x;
    x.u = ((unsigned)(unsigned short)s) << 16;
    return x.f;
}
__device__ __forceinline__ short f2bf(float f) {
    union { float f; unsigned u; } x; x.f = f;
    unsigned r = x.u + 0x7fff + ((x.u >> 16) & 1);   // round-nearest-even
    return (short)(r >> 16);
}
// dtype-adaptive loads: f32 flag selects float32 vs bf16 interpretation
__device__ __forceinline__ float ld1(const void* p, long long i, int f32) {
    return f32 ? ((const float*)p)[i] : bf2f(((const short*)p)[i]);
}
__device__ __forceinline__ short ldb1(const void* p, long long i, int f32) {
    return f32 ? f2bf(((const float*)p)[i]) : ((const short*)p)[i];
}
__device__ __forceinline__ bf16x8 ld8(const void* p, long long i, int f32) {
    bf16x8 r;
    if (f32) {
        const float* q = (const float*)p + i;
#pragma unroll
        for (int j = 0; j < 8; j++) r[j] = f2bf(q[j]);
    } else {
        r = *(const bf16x8*)((const short*)p + i);
    }
    return r;
}

// ---------------------------------------------------------------------------
// Kernel 0: dtype sniffer. Interpreting a float32 buffer as bf16 yields huge /
// NaN values from the random low mantissa bits; a real bf16 buffer of normals
// stays |x| < 10. flag = 1 -> buffers are float32.
// ---------------------------------------------------------------------------
__global__ void sniff_dtype(const void* q, int* flag) {
    __shared__ int bad;
    if (threadIdx.x == 0) bad = 0;
    __syncthreads();
    const short* s = (const short*)q;
    int tbad = 0;
    for (int i = threadIdx.x; i < 4096; i += 256) {
        float v = bf2f(s[i]);
        if (!(fabsf(v) < 1e4f)) tbad = 1;   // catches NaN too
    }
    if (tbad) atomicOr(&bad, 1);
    __syncthreads();
    if (threadIdx.x == 0) *flag = bad ? 1 : 0;
}

// ---------------------------------------------------------------------------
// Kernel 1: qa[b,h,i] = q[b,i,:] . Wq[:,h] + bq[h]  (and same for k)
// one wave per (b,i) row; lanes split D; per-lane 8 partial head sums.
// ---------------------------------------------------------------------------
__global__ __launch_bounds__(256) void proj_qk(
    const void* __restrict__ q, const void* __restrict__ k,
    const void* __restrict__ Wq, const void* __restrict__ bq,
    const void* __restrict__ Wk, const void* __restrict__ bk,
    float* __restrict__ qa, float* __restrict__ ka, const int* __restrict__ flagp)
{
    const int f32 = *flagp;
    int gtid = blockIdx.x * 256 + threadIdx.x;
    int row  = gtid >> 6;          // 0 .. B*L-1
    int lane = gtid & 63;
    int b = row >> 11, i = row & 2047;
    long long rbase = (long long)row * D_;
    float aq[8] = {0,0,0,0,0,0,0,0}, ak[8] = {0,0,0,0,0,0,0,0};
    for (int d0 = 0; d0 < D_; d0 += 64) {
        int d = d0 + lane;
        float qv = ld1(q, rbase + d, f32);
        float kv = ld1(k, rbase + d, f32);
#pragma unroll
        for (int h = 0; h < 8; h++) {
            aq[h] += qv * ld1(Wq, (long long)d * H_ + h, f32);
            ak[h] += kv * ld1(Wk, (long long)d * H_ + h, f32);
        }
    }
#pragma unroll
    for (int h = 0; h < 8; h++) {
#pragma unroll
        for (int st = 32; st >= 1; st >>= 1) {
            aq[h] += __shfl_xor(aq[h], st, 64);
            ak[h] += __shfl_xor(ak[h], st, 64);
        }
    }
    if (lane == 0) {
#pragma unroll
        for (int h = 0; h < 8; h++) {
            qa[((long long)(b * H_ + h)) * L_ + i] = aq[h] + ld1(bq, h, f32);
            ka[((long long)(b * H_ + h)) * L_ + i] = ak[h] + ld1(bk, h, f32);
        }
    }
}

// ---------------------------------------------------------------------------
// Generic batched MFMA bf16 GEMM: C = A(MxK) @ B(KxN) (+bias), 64x64x32 tiles.
// Modes: 0 = bf16, 1 = f32, 2 = use sniffed flag. aOff/bOff/cOff are element
// offsets applied after dtype resolution. batch z -> (zb, zh) strides.
// A-frag: A[m=lane&15][k=quad*8+j]; B staged transposed [n][k] in LDS;
// D[row=quad*4+r][col=lane&15]  (verified m89/m91/m92 layouts).
// ---------------------------------------------------------------------------
__global__ __launch_bounds__(256) void gemm_bf16(
    const void* __restrict__ A, long long aOff, int lda, long long sAb, long long sAh, int aMode,
    const void* __restrict__ Bm, long long bOff, int ldb, long long sBb, long long sBh, int bMode,
    const void* __restrict__ bias, int biasMode,
    void* __restrict__ C, long long cOff, int ldc, long long sCb, long long sCh, int cMode,
    int K, int nbh, const int* __restrict__ flagp)
{
    __shared__ __align__(16) short As[64][40];
    __shared__ __align__(16) short Bs[64][40];
    const int f = *flagp;
    const int fa = (aMode == 2) ? f : aMode;
    const int fb = (bMode == 2) ? f : bMode;
    const int fbias = (biasMode == 2) ? f : biasMode;
    const int fc = (cMode == 2) ? f : cMode;

    int z = blockIdx.z;
    int zb = z / nbh, zh = z % nbh;
    long long abase = aOff + (long long)zb * sAb + (long long)zh * sAh;
    long long bbase = bOff + (long long)zb * sBb + (long long)zh * sBh;
    long long cbase = cOff + (long long)zb * sCb + (long long)zh * sCh;

    int m0 = blockIdx.x * 64, n0 = blockIdx.y * 64;
    int tid = threadIdx.x;
    int lane = tid & 63, wave = tid >> 6;
    int wm = (wave & 1) * 32, wn = (wave >> 1) * 32;
    int qd = lane >> 4, ln = lane & 15;

    int arow = tid >> 2, acol = (tid & 3) * 8;   // A stage: 64 rows x 32 k
    int bn = tid & 63, bk0 = (tid >> 6) * 8;     // B stage: 32 k x 64 n

    floatx4 acc[2][2] = {};

    for (int k0 = 0; k0 < K; k0 += 32) {
        bf16x8 av = ld8(A, abase + (long long)(m0 + arow) * lda + k0 + acol, fa);
        bf16x8 bv;
#pragma unroll
        for (int jj = 0; jj < 8; jj++)
            bv[jj] = ldb1(Bm, bbase + (long long)(k0 + bk0 + jj) * ldb + n0 + bn, fb);
        __syncthreads();
        *(bf16x8*)&As[arow][acol] = av;
        *(bf16x8*)&Bs[bn][bk0] = bv;   // transposed: Bs[n][k]
        __syncthreads();
        bf16x8 a0 = *(const bf16x8*)&As[wm + ln][qd * 8];
        bf16x8 a1 = *(const bf16x8*)&As[wm + 16 + ln][qd * 8];
        bf16x8 b0 = *(const bf16x8*)&Bs[wn + ln][qd * 8];
        bf16x8 b1 = *(const bf16x8*)&Bs[wn + 16 + ln][qd * 8];
        acc[0][0] = __builtin_amdgcn_mfma_f32_16x16x32_bf16(a0, b0, acc[0][0], 0, 0, 0);
        acc[0][1] = __builtin_amdgcn_mfma_f32_16x16x32_bf16(a0, b1, acc[0][1], 0, 0, 0);
        acc[1][0] = __builtin_amdgcn_mfma_f32_16x16x32_bf16(a1, b0, acc[1][0], 0, 0, 0);
        acc[1][1] = __builtin_amdgcn_mfma_f32_16x16x32_bf16(a1, b1, acc[1][1], 0, 0, 0);
    }

#pragma unroll
    for (int ti = 0; ti < 2; ti++) {
#pragma unroll
        for (int tj = 0; tj < 2; tj++) {
            int col = n0 + wn + tj * 16 + ln;
            float bc = bias ? ld1(bias, col, fbias) : 0.f;
#pragma unroll
            for (int r = 0; r < 4; r++) {
                int row = m0 + wm + ti * 16 + qd * 4 + r;
                float val = acc[ti][tj][r] + bc;
                long long ci = cbase + (long long)row * ldc + col;
                if (fc) ((float*)C)[ci] = val;
                else    ((short*)C)[ci] = f2bf(val);
            }
        }
    }
}

// ---------------------------------------------------------------------------
// Kernel 3: scores -> softmax -> probs.  One block (256 thr) per (b,i).
// Heads processed in 2 groups of 4; each thread holds 8 j x 4 h scores in regs.
// probs written to d_out at element offset OUT0 in the sniffed dtype.
// ---------------------------------------------------------------------------
__global__ __launch_bounds__(256) void attn_probs(
    const void* __restrict__ dq_g,
    const void* __restrict__ dkt_g,
    const void* __restrict__ dkb_g,
    const void* __restrict__ dks_g,
    const void* __restrict__ Ww_g, const void* __restrict__ bw_g,
    const void* __restrict__ Wb_g, const void* __restrict__ bb_g,
    const float* __restrict__ qa_g, const float* __restrict__ ka_g,
    void* __restrict__ d_out, const int* __restrict__ flagp)
{
    __shared__ float red4[4][4];
    __shared__ float mh[4];
    __shared__ float invl[4];

    const int f32 = *flagp;
    int blk = blockIdx.x;
    int b = blk >> 11, i = blk & 2047;
    int tid = threadIdx.x;
    int lane = tid & 63, wave = tid >> 6;

    float dqv[3];
    {
        long long base = ((long long)(b * L_) + i) * C_;
        dqv[0] = ld1(dq_g, base + 0, f32);
        dqv[1] = ld1(dq_g, base + 1, f32);
        dqv[2] = ld1(dq_g, base + 2, f32);
    }
    const float* kabase = ka_g + (long long)b * H_ * L_;

    for (int g = 0; g < 2; g++) {
        // group weights (4 heads)
        float ww[3][4], wbm[3][4], bwv[4], bbv[4], qav[4];
#pragma unroll
        for (int h4 = 0; h4 < 4; h4++) {
            int h = g * 4 + h4;
#pragma unroll
            for (int c = 0; c < 3; c++) {
                ww[c][h4]  = ld1(Ww_g, c * H_ + h, f32);
                wbm[c][h4] = ld1(Wb_g, c * H_ + h, f32);
            }
            bwv[h4] = ld1(bw_g, h, f32);
            bbv[h4] = ld1(bb_g, h, f32);
            qav[h4] = qa_g[((long long)(b * H_ + h)) * L_ + i];
        }

        float sreg[8][4];   // [jl][h4], jl = it*2+jj, j = 2*tid + 512*it + jj
        float tmax[4] = {-1e30f, -1e30f, -1e30f, -1e30f};

#pragma unroll
        for (int it = 0; it < 4; it++) {
#pragma unroll
            for (int jj = 0; jj < 2; jj++) {
                int j = 2 * tid + 512 * it + jj;
                long long jb = ((long long)(b * L_) + j) * C_;
                long long sb = ((long long)(b * L_) + j) * (2 * C_);
                float f0, f1, f2;
                {
                    float kt0 = ld1(dkt_g, jb + 0, f32), kt1 = ld1(dkt_g, jb + 1, f32), kt2 = ld1(dkt_g, jb + 2, f32);
                    float kb0 = ld1(dkb_g, jb + 0, f32), kb1 = ld1(dkb_g, jb + 1, f32), kb2 = ld1(dkb_g, jb + 2, f32);
                    float s00 = ld1(dks_g, sb + 0, f32), s01 = ld1(dks_g, sb + 1, f32), s02 = ld1(dks_g, sb + 2, f32);
                    float s10 = ld1(dks_g, sb + 3, f32), s11 = ld1(dks_g, sb + 4, f32), s12 = ld1(dks_g, sb + 5, f32);
                    f0 = fabsf(dqv[0] - kt0) * s00 + fabsf(dqv[0] - kb0) * s10;
                    f1 = fabsf(dqv[1] - kt1) * s01 + fabsf(dqv[1] - kb1) * s11;
                    f2 = fabsf(dqv[2] - kt2) * s02 + fabsf(dqv[2] - kb2) * s12;
                }
#pragma unroll
                for (int h4 = 0; h4 < 4; h4++) {
                    int h = g * 4 + h4;
                    float gw = bwv[h4] + f0 * ww[0][h4] + f1 * ww[1][h4] + f2 * ww[2][h4];
                    float e  = __expf(gw);
                    float dwv = (gw > 15.f) ? gw : __logf(1.f + e);
                    float gb = bbv[h4] + f0 * wbm[0][h4] + f1 * wbm[1][h4] + f2 * wbm[2][h4];
                    float kaj = kabase[h * L_ + j];
                    float s = qav[h4] * kaj * dwv + gb;
                    sreg[it * 2 + jj][h4] = s;
                    tmax[h4] = fmaxf(tmax[h4], s);
                }
            }
        }

        // block max per head
#pragma unroll
        for (int h4 = 0; h4 < 4; h4++)
#pragma unroll
            for (int st = 32; st >= 1; st >>= 1)
                tmax[h4] = fmaxf(tmax[h4], __shfl_xor(tmax[h4], st, 64));
        if (lane == 0) {
#pragma unroll
            for (int h4 = 0; h4 < 4; h4++) red4[h4][wave] = tmax[h4];
        }
        __syncthreads();
        if (tid == 0) {
#pragma unroll
            for (int h4 = 0; h4 < 4; h4++)
                mh[h4] = fmaxf(fmaxf(red4[h4][0], red4[h4][1]), fmaxf(red4[h4][2], red4[h4][3]));
        }
        __syncthreads();

        // exp + sum
        float tsum[4] = {0.f, 0.f, 0.f, 0.f};
#pragma unroll
        for (int jl = 0; jl < 8; jl++) {
#pragma unroll
            for (int h4 = 0; h4 < 4; h4++) {
                float e = __expf(sreg[jl][h4] - mh[h4]);
                sreg[jl][h4] = e;
                tsum[h4] += e;
            }
        }
#pragma unroll
        for (int h4 = 0; h4 < 4; h4++)
#pragma unroll
            for (int st = 32; st >= 1; st >>= 1)
                tsum[h4] += __shfl_xor(tsum[h4], st, 64);
        __syncthreads();   // red4 reuse
        if (lane == 0) {
#pragma unroll
            for (int h4 = 0; h4 < 4; h4++) red4[h4][wave] = tsum[h4];
        }
        __syncthreads();
        if (tid == 0) {
#pragma unroll
            for (int h4 = 0; h4 < 4; h4++)
                invl[h4] = 1.f / (red4[h4][0] + red4[h4][1] + red4[h4][2] + red4[h4][3]);
        }
        __syncthreads();

        // normalize + store pairs (j, j+1)
#pragma unroll
        for (int it = 0; it < 4; it++) {
            int j = 2 * tid + 512 * it;
#pragma unroll
            for (int h4 = 0; h4 < 4; h4++) {
                int h = g * 4 + h4;
                float p0 = sreg[it * 2 + 0][h4] * invl[h4];
                float p1 = sreg[it * 2 + 1][h4] * invl[h4];
                long long idx = ((long long)(b * H_ + h) * L_ + i) * L_ + j;
                if (f32) {
                    float2 pp; pp.x = p0; pp.y = p1;
                    *(float2*)((float*)d_out + OUT0 + idx) = pp;
                } else {
                    unsigned pk = (unsigned)(unsigned short)f2bf(p0)
                                | ((unsigned)(unsigned short)f2bf(p1) << 16);
                    *((unsigned*)((short*)d_out + OUT0) + (idx >> 1)) = pk;
                }
            }
        }
        __syncthreads();
    }
}

// ---------------------------------------------------------------------------
extern "C" void kernel_launch(void* const* d_in, const int* in_sizes, int n_in,
                              void* d_out, int out_size, void* d_ws, size_t ws_size,
                              hipStream_t stream)
{
    const void* q   = d_in[0];
    const void* k   = d_in[1];
    const void* v   = d_in[2];
    const void* dq  = d_in[3];
    const void* dkt = d_in[4];
    const void* dkb = d_in[5];
    const void* dks = d_in[6];
    const void* Wq  = d_in[7];
    const void* bq  = d_in[8];
    const void* Wk  = d_in[9];
    const void* bk  = d_in[10];
    // d_in[11] Wc, d_in[12] bc: unused by the reference
    const void* Wv  = d_in[13];
    const void* bv  = d_in[14];
    const void* Wo  = d_in[15];
    const void* bo  = d_in[16];
    const void* Ww  = d_in[17];
    const void* bw  = d_in[18];
    const void* Wb  = d_in[19];
    const void* bb  = d_in[20];

    // workspace layout (~16.9 MB)
    int*   flag  = (int*)d_ws;                                  // 1 int
    float* qa    = (float*)((char*)d_ws + 1024);                // B*H*L f32
    float* ka    = qa + (size_t)B_ * H_ * L_;
    short* vproj = (short*)((char*)d_ws + 525312);              // B*L*D bf16 (16B aligned)
    short* attn  = vproj + OUT0;                                // B*L*D bf16

    // 0. dtype sniff
    sniff_dtype<<<dim3(1), 256, 0, stream>>>(q, flag);

    // 1. qa / ka projections
    proj_qk<<<dim3(B_ * L_ * 64 / 256), 256, 0, stream>>>(q, k, Wq, bq, Wk, bk, qa, ka, flag);

    // 2. vproj = v @ Wv + bv   (bf16 intermediate in ws)
    gemm_bf16<<<dim3(B_ * L_ / 64, D_ / 64, 1), 256, 0, stream>>>(
        v, 0, D_, 0, 0, 2,
        Wv, 0, D_, 0, 0, 2,
        bv, 2,
        (void*)vproj, 0, D_, 0, 0, 0,
        D_, 1, flag);

    // 3. scores -> softmax -> probs (written into d_out at element OUT0)
    attn_probs<<<dim3(B_ * L_), 256, 0, stream>>>(
        dq, dkt, dkb, dks, Ww, bw, Wb, bb, qa, ka, d_out, flag);

    // 4. attn[b,i,h*64+dh] = sum_j probs[b,h,i,j] * vproj[b,j,h*64+dh]
    gemm_bf16<<<dim3(L_ / 64, 1, B_ * H_), 256, 0, stream>>>(
        d_out, OUT0, L_, (long long)H_ * L_ * L_, (long long)L_ * L_, 2,
        vproj, 0, D_, (long long)L_ * D_, DH_, 0,
        nullptr, 0,
        (void*)attn, 0, D_, (long long)L_ * D_, DH_, 0,
        L_, H_, flag);

    // 5. out = attn @ Wo + bo  (into d_out[0..B*L*D), sniffed dtype)
    gemm_bf16<<<dim3(B_ * L_ / 64, D_ / 64, 1), 256, 0, stream>>>(
        attn, 0, D_, 0, 0, 0,
        Wo, 0, D_, 0, 0, 2,
        bo, 2,
        d_out, 0, D_, 0, 0, 2,
        D_, 1, flag);
}